// Round 1
// baseline (2356.644 us; speedup 1.0000x reference)
//
#include <hip/hip_runtime.h>
#include <math.h>

// Problem constants
#define BB 4
#define SQL 2048
#define SKL 2048
#define DD 1024
#define HH 16
#define DKV 64

// Workspace layout (float offsets)
#define OFF_WPQ  (0u)
#define OFF_WPK  (1u<<20)
#define OFF_WPV  (2u<<20)
#define OFF_WBIG (3u<<20)
#define OFF_BC   (4u<<20)
#define OFF_Q    ((4u<<20) + 4096u)
#define OFF_K    (OFF_Q + (8u<<20))
#define OFF_V    (OFF_K + (8u<<20))
#define OFF_CTX  (OFF_V + (8u<<20))
// total = 4M + 4096 + 32M floats  ~= 144 MB

// ---------------------------------------------------------------------------
// Pack Wq/Wk/Wv from [H, D, DK] to [D, H*DK] so projections are plain GEMMs.
__global__ __launch_bounds__(256) void pack_qkv(const float* __restrict__ Wq,
                                                const float* __restrict__ Wk,
                                                const float* __restrict__ Wv,
                                                float* __restrict__ ws) {
    unsigned idx = blockIdx.x * 256u + threadIdx.x;   // over 1024*1024
    unsigned d = idx >> 10, j = idx & 1023u;
    unsigned h = j >> 6, kk = j & 63u;
    unsigned src = (h * 1024u + d) * 64u + kk;        // h*D*DK + d*DK + kk
    ws[OFF_WPQ + idx] = Wq[src];
    ws[OFF_WPK + idx] = Wk[src];
    ws[OFF_WPV + idx] = Wv[src];
}

// Wbig[h*64+v][j] = sum_u Wo[h][v][u] * Wf[h*64+u][j]
// bcomb[j] = bf[j] + sum_x bo[x] * Wf[x][j]
__global__ __launch_bounds__(256) void make_wbig(const float* __restrict__ Wo,
                                                 const float* __restrict__ Wf,
                                                 const float* __restrict__ bo,
                                                 const float* __restrict__ bf,
                                                 float* __restrict__ wbig,
                                                 float* __restrict__ bcomb) {
    unsigned idx = blockIdx.x * 256u + threadIdx.x;   // over 1024*1024
    unsigned i = idx >> 10;       // row = h*64 + v
    unsigned j = idx & 1023u;     // col
    unsigned h = i >> 6;
    float s = 0.f;
#pragma unroll 8
    for (int u = 0; u < 64; ++u)
        s += Wo[i * 64u + u] * Wf[(h * 64u + u) * 1024u + j];
    wbig[idx] = s;
    if (i == 0) {
        float t = bf[j];
        for (int x = 0; x < 1024; ++x) t += bo[x] * Wf[x * 1024u + j];
        bcomb[j] = t;
    }
}

// ---------------------------------------------------------------------------
// fp32 GEMM: C[M,N] = A[M,K] @ Bm[K,N] + bias[N].  128x128 tile, BK=16,
// 256 threads, 8x8 per thread.
__global__ __launch_bounds__(256) void gemm128(const float* __restrict__ A,
                                               const float* __restrict__ Bm,
                                               const float* __restrict__ bias,
                                               float* __restrict__ C,
                                               int M, int N, int K) {
    __shared__ float As[16][128];   // [k][m]  (transposed on store)
    __shared__ float Bs[16][128];   // [k][n]
    const int tid = threadIdx.x;
    const int bm = blockIdx.y * 128, bn = blockIdx.x * 128;
    const int tx = tid & 15, ty = tid >> 4;

    float acc[8][8] = {};

    for (int k0 = 0; k0 < K; k0 += 16) {
        // Stage A tile: 128 rows x 16 k. thread: row=tid>>1, kc=(tid&1)*8
        {
            int r = tid >> 1, kc = (tid & 1) * 8;
            const float* ap = A + (size_t)(bm + r) * K + k0 + kc;
            float4 a0 = *(const float4*)ap;
            float4 a1 = *(const float4*)(ap + 4);
            As[kc + 0][r] = a0.x; As[kc + 1][r] = a0.y;
            As[kc + 2][r] = a0.z; As[kc + 3][r] = a0.w;
            As[kc + 4][r] = a1.x; As[kc + 5][r] = a1.y;
            As[kc + 6][r] = a1.z; As[kc + 7][r] = a1.w;
            // Stage B tile: 16 k-rows x 128 n. thread: kr=tid>>4, nc=(tid&15)*8
            int kr = tid >> 4, nc = (tid & 15) * 8;
            const float* bp = Bm + (size_t)(k0 + kr) * N + bn + nc;
            float4 b0 = *(const float4*)bp;
            float4 b1 = *(const float4*)(bp + 4);
            *(float4*)&Bs[kr][nc]     = b0;
            *(float4*)&Bs[kr][nc + 4] = b1;
        }
        __syncthreads();
#pragma unroll
        for (int kk = 0; kk < 16; ++kk) {
            float a[8], b[8];
            *(float4*)(a)     = *(const float4*)&As[kk][ty * 8];
            *(float4*)(a + 4) = *(const float4*)&As[kk][ty * 8 + 4];
            *(float4*)(b)     = *(const float4*)&Bs[kk][tx * 8];
            *(float4*)(b + 4) = *(const float4*)&Bs[kk][tx * 8 + 4];
#pragma unroll
            for (int i = 0; i < 8; ++i)
#pragma unroll
                for (int j = 0; j < 8; ++j)
                    acc[i][j] += a[i] * b[j];
        }
        __syncthreads();
    }

    float bfr[8];
    *(float4*)(bfr)     = *(const float4*)(bias + bn + tx * 8);
    *(float4*)(bfr + 4) = *(const float4*)(bias + bn + tx * 8 + 4);
#pragma unroll
    for (int i = 0; i < 8; ++i) {
        int r = bm + ty * 8 + i;
        float4 o0, o1;
        o0.x = acc[i][0] + bfr[0]; o0.y = acc[i][1] + bfr[1];
        o0.z = acc[i][2] + bfr[2]; o0.w = acc[i][3] + bfr[3];
        o1.x = acc[i][4] + bfr[4]; o1.y = acc[i][5] + bfr[5];
        o1.z = acc[i][6] + bfr[6]; o1.w = acc[i][7] + bfr[7];
        float* cp = C + (size_t)r * N + bn + tx * 8;
        *(float4*)cp       = o0;
        *(float4*)(cp + 4) = o1;
    }
}

// ---------------------------------------------------------------------------
// Causal flash attention, fp32.  q/k/v/ctx layout: [B, S, H*64].
// Block: (q-tile of 64 rows) x (b*H).  256 threads, 4x4 per thread.
#define NEG_BIG (-1e30f)
__global__ __launch_bounds__(256) void flash_attn(const float* __restrict__ q,
                                                  const float* __restrict__ k,
                                                  const float* __restrict__ v,
                                                  const unsigned char* __restrict__ pmask,
                                                  float* __restrict__ ctx) {
    const int bh = blockIdx.y;
    const int b = bh >> 4, h = bh & 15;
    const int qt = blockIdx.x;          // 0..31
    const int tid = threadIdx.x;
    const int tx = tid & 15, ty = tid >> 4;

    __shared__ float Qs[64][64];  // [d][r]
    __shared__ float Ks[64][64];  // [d][c]
    __shared__ float Vs[64][64];  // [c][d]  (column-swizzled)
    __shared__ float Ps[64][64];  // [r][c]  (column-swizzled)

    // Load Q tile transposed: Qs[d][r]
    {
        int r = tid >> 2, db = (tid & 3) * 16;
        const float* qp = q + ((size_t)b * SQL + qt * 64 + r) * 1024 + h * 64 + db;
#pragma unroll
        for (int t = 0; t < 16; t += 4) {
            float4 x = *(const float4*)(qp + t);
            Qs[db + t + 0][r] = x.x; Qs[db + t + 1][r] = x.y;
            Qs[db + t + 2][r] = x.z; Qs[db + t + 3][r] = x.w;
        }
    }

    float m_i[4], l_i[4];
    float acc[4][4] = {};
#pragma unroll
    for (int i = 0; i < 4; ++i) { m_i[i] = NEG_BIG; l_i[i] = 0.f; }

    const unsigned char* pm = pmask + (size_t)b * SKL;
    const int nkt = qt + 1;   // causal

    for (int kt = 0; kt < nkt; ++kt) {
        __syncthreads();   // protect K/V/P reuse
        {
            int c = tid >> 2, db = (tid & 3) * 16;
            const float* kp = k + ((size_t)b * SKL + kt * 64 + c) * 1024 + h * 64 + db;
            const float* vp = v + ((size_t)b * SKL + kt * 64 + c) * 1024 + h * 64 + db;
            int swz = (c & 7) << 2;
#pragma unroll
            for (int t = 0; t < 16; t += 4) {
                float4 x = *(const float4*)(kp + t);
                Ks[db + t + 0][c] = x.x; Ks[db + t + 1][c] = x.y;
                Ks[db + t + 2][c] = x.z; Ks[db + t + 3][c] = x.w;
                float4 y = *(const float4*)(vp + t);
                *(float4*)&Vs[c][(db + t) ^ swz] = y;
            }
        }
        __syncthreads();

        // S = (q . k^T) * scale
        float s[4][4] = {};
#pragma unroll
        for (int d = 0; d < 64; ++d) {
            float aq[4], bk_[4];
            *(float4*)aq  = *(const float4*)&Qs[d][ty * 4];
            *(float4*)bk_ = *(const float4*)&Ks[d][tx * 4];
#pragma unroll
            for (int i = 0; i < 4; ++i)
#pragma unroll
                for (int j = 0; j < 4; ++j)
                    s[i][j] += aq[i] * bk_[j];
        }

        const int kc0 = kt * 64 + tx * 4;
        float mcol[4];
#pragma unroll
        for (int j = 0; j < 4; ++j) mcol[j] = pm[kc0 + j] ? NEG_BIG : 0.f;

        const int qr0 = qt * 64 + ty * 4;
#pragma unroll
        for (int i = 0; i < 4; ++i)
#pragma unroll
            for (int j = 0; j < 4; ++j) {
                float val = s[i][j] * 0.125f + mcol[j];
                if (kt == qt && (kc0 + j) > (qr0 + i)) val = NEG_BIG;
                s[i][j] = val;
            }

        // Row max across this tile (reduce over tx: 16 lanes)
        float rmax[4];
#pragma unroll
        for (int i = 0; i < 4; ++i)
            rmax[i] = fmaxf(fmaxf(s[i][0], s[i][1]), fmaxf(s[i][2], s[i][3]));
#pragma unroll
        for (int off = 1; off < 16; off <<= 1)
#pragma unroll
            for (int i = 0; i < 4; ++i)
                rmax[i] = fmaxf(rmax[i], __shfl_xor(rmax[i], off, 64));

        float mnew[4], alpha[4];
#pragma unroll
        for (int i = 0; i < 4; ++i) {
            mnew[i]  = fmaxf(m_i[i], rmax[i]);
            alpha[i] = __expf(m_i[i] - mnew[i]);
            m_i[i]   = mnew[i];
        }

        // P = exp(S - mnew); row sums
        float p[4][4], rsum[4];
#pragma unroll
        for (int i = 0; i < 4; ++i) {
            rsum[i] = 0.f;
#pragma unroll
            for (int j = 0; j < 4; ++j) {
                p[i][j] = __expf(s[i][j] - mnew[i]);
                rsum[i] += p[i][j];
            }
        }
#pragma unroll
        for (int off = 1; off < 16; off <<= 1)
#pragma unroll
            for (int i = 0; i < 4; ++i)
                rsum[i] += __shfl_xor(rsum[i], off, 64);

#pragma unroll
        for (int i = 0; i < 4; ++i) {
            l_i[i] = l_i[i] * alpha[i] + rsum[i];
#pragma unroll
            for (int j = 0; j < 4; ++j) acc[i][j] *= alpha[i];
        }

        // Write P to LDS (swizzled), then PV
#pragma unroll
        for (int i = 0; i < 4; ++i) {
            int r = ty * 4 + i;
            float4 pv; pv.x = p[i][0]; pv.y = p[i][1]; pv.z = p[i][2]; pv.w = p[i][3];
            *(float4*)&Ps[r][(tx * 4) ^ ((r & 7) << 2)] = pv;
        }
        __syncthreads();

#pragma unroll
        for (int c = 0; c < 64; ++c) {
            float vv[4];
            *(float4*)vv = *(const float4*)&Vs[c][(tx * 4) ^ ((c & 7) << 2)];
            float pp[4];
#pragma unroll
            for (int i = 0; i < 4; ++i) {
                int r = ty * 4 + i;
                pp[i] = Ps[r][c ^ ((r & 7) << 2)];
            }
#pragma unroll
            for (int i = 0; i < 4; ++i)
#pragma unroll
                for (int j = 0; j < 4; ++j)
                    acc[i][j] += pp[i] * vv[j];
        }
    }

    // Epilogue: O / l  -> ctx[b, s, h*64 + vcol]
#pragma unroll
    for (int i = 0; i < 4; ++i) {
        float inv = 1.f / l_i[i];
        float4 o;
        o.x = acc[i][0] * inv; o.y = acc[i][1] * inv;
        o.z = acc[i][2] * inv; o.w = acc[i][3] * inv;
        size_t row = (size_t)b * SQL + qt * 64 + ty * 4 + i;
        *(float4*)(ctx + row * 1024 + h * 64 + tx * 4) = o;
    }
}

// ---------------------------------------------------------------------------
extern "C" void kernel_launch(void* const* d_in, const int* in_sizes, int n_in,
                              void* d_out, int out_size, void* d_ws, size_t ws_size,
                              hipStream_t stream) {
    const float* Q  = (const float*)d_in[0];
    const float* K  = (const float*)d_in[1];
    const float* V  = (const float*)d_in[2];
    const unsigned char* pmask = (const unsigned char*)d_in[3];
    const float* Wq = (const float*)d_in[4];
    const float* bq = (const float*)d_in[5];
    const float* Wk = (const float*)d_in[6];
    const float* bk = (const float*)d_in[7];
    const float* Wv = (const float*)d_in[8];
    const float* bv = (const float*)d_in[9];
    const float* Wo = (const float*)d_in[10];
    const float* bo = (const float*)d_in[11];
    const float* Wf = (const float*)d_in[12];
    const float* bf = (const float*)d_in[13];
    float* out = (float*)d_out;
    float* ws  = (float*)d_ws;

    pack_qkv<<<4096, 256, 0, stream>>>(Wq, Wk, Wv, ws);
    make_wbig<<<4096, 256, 0, stream>>>(Wo, Wf, bo, bf, ws + OFF_WBIG, ws + OFF_BC);

    dim3 g1(8, 64);   // N/128, M/128
    gemm128<<<g1, 256, 0, stream>>>(Q, ws + OFF_WPQ, bq, ws + OFF_Q, 8192, 1024, 1024);
    gemm128<<<g1, 256, 0, stream>>>(K, ws + OFF_WPK, bk, ws + OFF_K, 8192, 1024, 1024);
    gemm128<<<g1, 256, 0, stream>>>(V, ws + OFF_WPV, bv, ws + OFF_V, 8192, 1024, 1024);

    flash_attn<<<dim3(32, 64), 256, 0, stream>>>(ws + OFF_Q, ws + OFF_K, ws + OFF_V,
                                                 pmask, ws + OFF_CTX);

    gemm128<<<g1, 256, 0, stream>>>(ws + OFF_CTX, ws + OFF_WBIG, ws + OFF_BC, out,
                                    8192, 1024, 1024);
}

// Round 2
// 622.985 us; speedup vs baseline: 3.7828x; 3.7828x over previous
//
#include <hip/hip_runtime.h>

typedef unsigned short u16;
typedef __attribute__((ext_vector_type(8))) short short8;
typedef __attribute__((ext_vector_type(4))) float f32x4;

#define NEG (-1e30f)

// ---- workspace byte offsets -------------------------------------------------
#define WS_WPQ   (0u)          // 2 MB  bf16 [N=1024][K=1024]  (B^T)
#define WS_WPK   (2u<<20)
#define WS_WPV   (4u<<20)
#define WS_WBIG  (6u<<20)      // 2 MB  bf16 B^T
#define WS_BC    (8u<<20)      // 4 KB  f32
#define WS_QB    (9u<<20)      // 16 MB bf16 [8192][1024]
#define WS_KB    (25u<<20)
#define WS_VB    (41u<<20)
#define WS_QP    (57u<<20)     // q projection bf16
#define WS_KP    (73u<<20)
#define WS_VP    (89u<<20)
#define WS_VT    (105u<<20)    // V^T, pre-swizzled: [bh*64+dv][2048 kv]
#define WS_CTX   (121u<<20)    // attention out bf16

// ---- helpers ----------------------------------------------------------------
__device__ __forceinline__ u16 f2b(float f) {
    union { float f; unsigned u; } x; x.f = f;
    unsigned r = x.u + 0x7fffu + ((x.u >> 16) & 1u);   // RNE
    return (u16)(r >> 16);
}

__device__ __forceinline__ void gload16(const void* g, void* lds) {
    __builtin_amdgcn_global_load_lds(
        (const __attribute__((address_space(1))) void*)g,
        (__attribute__((address_space(3))) void*)lds, 16, 0, 0);
}

// ---- small prep kernels -----------------------------------------------------
__global__ __launch_bounds__(256) void conv_bf16(const float* __restrict__ in,
                                                 u16* __restrict__ out) {
    unsigned i = blockIdx.x * 256u + threadIdx.x;      // 1M threads, 8 elems each
    const float4* p = (const float4*)(in + (size_t)i * 8);
    float4 a = p[0], b = p[1];
    short8 o;
    o[0]=(short)f2b(a.x); o[1]=(short)f2b(a.y); o[2]=(short)f2b(a.z); o[3]=(short)f2b(a.w);
    o[4]=(short)f2b(b.x); o[5]=(short)f2b(b.y); o[6]=(short)f2b(b.z); o[7]=(short)f2b(b.w);
    *(short8*)(out + (size_t)i * 8) = o;
}

// Wq/Wk/Wv [H,D,64] -> B^T bf16 [n=h*64+kk][k=d]
__global__ __launch_bounds__(256) void pack_qkv(const float* __restrict__ Wq,
                                                const float* __restrict__ Wk,
                                                const float* __restrict__ Wv,
                                                u16* __restrict__ pq,
                                                u16* __restrict__ pk,
                                                u16* __restrict__ pv) {
    unsigned idx = blockIdx.x * 256u + threadIdx.x;    // 1M
    unsigned n = idx >> 10, d = idx & 1023u;
    unsigned h = n >> 6, kk = n & 63u;
    unsigned src = (h * 1024u + d) * 64u + kk;
    pq[idx] = f2b(Wq[src]);
    pk[idx] = f2b(Wk[src]);
    pv[idx] = f2b(Wv[src]);
}

// WbigT[n][k] = sum_u Wo[k][u] * Wf[(k/64)*64+u][n]   (bf16 out)
__global__ __launch_bounds__(256) void make_wbig(const float* __restrict__ Wo,
                                                 const float* __restrict__ Wf,
                                                 u16* __restrict__ wbig) {
    unsigned idx = blockIdx.x * 256u + threadIdx.x;    // 1M
    unsigned n = idx >> 10, k = idx & 1023u;
    unsigned h = k >> 6;
    float s = 0.f;
#pragma unroll 8
    for (int u = 0; u < 64; ++u)
        s += Wo[k * 64u + u] * Wf[(h * 64u + u) * 1024u + n];
    wbig[(size_t)n * 1024u + k] = f2b(s);
}

// bcomb[n] = bf[n] + sum_x bo[x] * Wf[x][n]
__global__ __launch_bounds__(256) void make_bcomb(const float* __restrict__ bo,
                                                  const float* __restrict__ bf,
                                                  const float* __restrict__ Wf,
                                                  float* __restrict__ bc) {
    int n = blockIdx.x * 256 + threadIdx.x;            // 1024 threads
    float t = bf[n];
    for (int x = 0; x < 1024; ++x) t += bo[x] * Wf[(size_t)x * 1024 + n];
    bc[n] = t;
}

// v bf16 [B,2048,1024] -> Vt bf16 [bh*64+dv][2048], kv-chunks XOR-swizzled by dv
__global__ __launch_bounds__(256) void vtrans(const u16* __restrict__ vp,
                                              u16* __restrict__ vt) {
    const int kvt = blockIdx.x, bh = blockIdx.y, b = bh >> 4, h = bh & 15;
    const int tid = threadIdx.x;
    __shared__ u16 T[64][72];
    {
        int kv_r = tid >> 2, dg = (tid & 3) * 16;
        const u16* src = vp + ((size_t)(b * 2048 + kvt * 64 + kv_r)) * 1024 + h * 64 + dg;
        short8 x0 = *(const short8*)src;
        short8 x1 = *(const short8*)(src + 8);
#pragma unroll
        for (int i = 0; i < 8; ++i) { T[dg + i][kv_r] = (u16)x0[i]; T[dg + 8 + i][kv_r] = (u16)x1[i]; }
    }
    __syncthreads();
    {
        int dv = tid >> 2, cg = (tid & 3) * 16;
        int swz = (dv & 7) << 3;
        u16* dst = vt + ((size_t)(bh * 64 + dv)) * 2048 + kvt * 64;
#pragma unroll
        for (int q = 0; q < 2; ++q) {
            int c0 = cg + q * 8;
            short8 y;
#pragma unroll
            for (int i = 0; i < 8; ++i) y[i] = (short)T[dv][c0 + i];
            *(short8*)(dst + (c0 ^ swz)) = y;
        }
    }
}

// ---- bf16 MFMA GEMM: C = A[M,K] @ Bt[N,K]^T + bias --------------------------
// 128x128 tile, BK=64, 4 waves, global_load_lds staging with XOR-swizzled source.
template <int OUT_BF16>
__global__ __launch_bounds__(256) void gemm_bf16(const u16* __restrict__ A,
                                                 const u16* __restrict__ Bt,
                                                 const float* __restrict__ bias,
                                                 void* __restrict__ Cv,
                                                 int M, int N, int K) {
    __shared__ __align__(16) u16 As[128 * 64];
    __shared__ __align__(16) u16 Bs[128 * 64];
    const int tid = threadIdx.x;
    const int lane = tid & 63, w = tid >> 6;
    const int li = lane & 15, g = lane >> 4;
    const int bm = blockIdx.y * 128, bn = blockIdx.x * 128;
    const int wm = w >> 1, wn = w & 1;

    f32x4 acc[4][4];
#pragma unroll
    for (int m = 0; m < 4; ++m)
#pragma unroll
        for (int n = 0; n < 4; ++n) acc[m][n] = (f32x4){0.f, 0.f, 0.f, 0.f};

    for (int k0 = 0; k0 < K; k0 += 64) {
        __syncthreads();
#pragma unroll
        for (int r = 0; r < 4; ++r) {
            int ch  = (r * 4 + w) * 64 + lane;          // 0..1023
            int row = ch >> 3;
            int ck  = (ch & 7) ^ (row & 7);             // pre-swizzled source chunk
            gload16(A  + (size_t)(bm + row) * K + k0 + ck * 8, (char*)As + (r * 4 + w) * 1024);
            gload16(Bt + (size_t)(bn + row) * K + k0 + ck * 8, (char*)Bs + (r * 4 + w) * 1024);
        }
        __syncthreads();
#pragma unroll
        for (int kk = 0; kk < 2; ++kk) {
            short8 a[4], b[4];
#pragma unroll
            for (int m = 0; m < 4; ++m) {
                int row = wm * 64 + m * 16 + li;
                int c = (kk * 4 + g) ^ (row & 7);
                a[m] = *(const short8*)(As + row * 64 + c * 8);
            }
#pragma unroll
            for (int n = 0; n < 4; ++n) {
                int row = wn * 64 + n * 16 + li;
                int c = (kk * 4 + g) ^ (row & 7);
                b[n] = *(const short8*)(Bs + row * 64 + c * 8);
            }
#pragma unroll
            for (int m = 0; m < 4; ++m)
#pragma unroll
                for (int n = 0; n < 4; ++n)
                    acc[m][n] = __builtin_amdgcn_mfma_f32_16x16x32_bf16(a[m], b[n], acc[m][n], 0, 0, 0);
        }
    }

#pragma unroll
    for (int n = 0; n < 4; ++n) {
        int col = bn + wn * 64 + n * 16 + li;
        float bv = bias[col];
#pragma unroll
        for (int m = 0; m < 4; ++m)
#pragma unroll
            for (int j = 0; j < 4; ++j) {
                int row = bm + wm * 64 + m * 16 + g * 4 + j;
                float v = acc[m][n][j] + bv;
                if (OUT_BF16) ((u16*)Cv)[(size_t)row * N + col] = f2b(v);
                else          ((float*)Cv)[(size_t)row * N + col] = v;
            }
    }
}

// ---- bf16 MFMA causal flash attention --------------------------------------
// QT=64, KVT=64, 4 waves; wave w owns q rows [w*16, w*16+16).
__global__ __launch_bounds__(256) void flash_attn(const u16* __restrict__ qp,
                                                  const u16* __restrict__ kp,
                                                  const u16* __restrict__ vt,
                                                  const unsigned char* __restrict__ pmask,
                                                  u16* __restrict__ ctx) {
    const int qt = 31 - blockIdx.x;                    // longest blocks first
    const int bh = blockIdx.y, b = bh >> 4, h = bh & 15;
    const int tid = threadIdx.x, lane = tid & 63, w = tid >> 6;
    const int li = lane & 15, g = lane >> 4;

    __shared__ __align__(16) u16 Qs[64 * 64];
    __shared__ __align__(16) u16 Ks[64 * 64];
    __shared__ __align__(16) u16 Vs[64 * 64];
    __shared__ __align__(16) u16 Ps[64 * 64];

    // stage Q tile (swizzled source)
#pragma unroll
    for (int r = 0; r < 2; ++r) {
        int ch  = (r * 4 + w) * 64 + lane;             // 0..511
        int row = ch >> 3;
        int ck  = (ch & 7) ^ (row & 7);
        gload16(qp + (size_t)(b * 2048 + qt * 64 + row) * 1024 + h * 64 + ck * 8,
                (char*)Qs + (r * 4 + w) * 1024);
    }

    float m_i[4], l_i[4];
    f32x4 o_acc[4];
#pragma unroll
    for (int j = 0; j < 4; ++j) { m_i[j] = NEG; l_i[j] = 0.f; }
#pragma unroll
    for (int n = 0; n < 4; ++n) o_acc[n] = (f32x4){0.f, 0.f, 0.f, 0.f};

    const unsigned char* pm = pmask + (size_t)b * 2048;

    for (int kt = 0; kt <= qt; ++kt) {
        __syncthreads();
#pragma unroll
        for (int r = 0; r < 2; ++r) {
            int ch  = (r * 4 + w) * 64 + lane;
            int row = ch >> 3, cc = ch & 7;
            int ck  = cc ^ (row & 7);
            gload16(kp + (size_t)(b * 2048 + kt * 64 + row) * 1024 + h * 64 + ck * 8,
                    (char*)Ks + (r * 4 + w) * 1024);
            gload16(vt + (size_t)(bh * 64 + row) * 2048 + kt * 64 + cc * 8,   // pre-swizzled
                    (char*)Vs + (r * 4 + w) * 1024);
        }
        __syncthreads();

        // S = Q K^T
        f32x4 s[4];
#pragma unroll
        for (int n = 0; n < 4; ++n) s[n] = (f32x4){0.f, 0.f, 0.f, 0.f};
#pragma unroll
        for (int kk = 0; kk < 2; ++kk) {
            int rq = w * 16 + li;
            short8 aq = *(const short8*)(Qs + rq * 64 + (((kk * 4 + g) ^ (li & 7))) * 8);
#pragma unroll
            for (int n = 0; n < 4; ++n) {
                int rk = n * 16 + li;
                short8 bk = *(const short8*)(Ks + rk * 64 + (((kk * 4 + g) ^ (li & 7))) * 8);
                s[n] = __builtin_amdgcn_mfma_f32_16x16x32_bf16(aq, bk, s[n], 0, 0, 0);
            }
        }

        // mask + scale
        float mcol[4];
#pragma unroll
        for (int n = 0; n < 4; ++n) mcol[n] = pm[kt * 64 + n * 16 + li] ? NEG : 0.f;
        const bool diag = (kt == qt);
        float rmax[4];
#pragma unroll
        for (int j = 0; j < 4; ++j) rmax[j] = NEG;
#pragma unroll
        for (int n = 0; n < 4; ++n) {
            int colk = kt * 64 + n * 16 + li;
#pragma unroll
            for (int j = 0; j < 4; ++j) {
                int rowq = qt * 64 + w * 16 + g * 4 + j;
                float v = s[n][j] * 0.125f + mcol[n];
                if (diag && colk > rowq) v = NEG;
                s[n][j] = v;
                rmax[j] = fmaxf(rmax[j], v);
            }
        }
#pragma unroll
        for (int off = 1; off < 16; off <<= 1)
#pragma unroll
            for (int j = 0; j < 4; ++j)
                rmax[j] = fmaxf(rmax[j], __shfl_xor(rmax[j], off));

        float alpha[4];
#pragma unroll
        for (int j = 0; j < 4; ++j) {
            float mn = fmaxf(m_i[j], rmax[j]);
            alpha[j] = __expf(m_i[j] - mn);
            m_i[j] = mn;
        }

        float p[4][4], rsum[4] = {0.f, 0.f, 0.f, 0.f};
#pragma unroll
        for (int n = 0; n < 4; ++n)
#pragma unroll
            for (int j = 0; j < 4; ++j) {
                float pv = __expf(s[n][j] - m_i[j]);
                p[n][j] = pv;
                rsum[j] += pv;
            }
#pragma unroll
        for (int off = 1; off < 16; off <<= 1)
#pragma unroll
            for (int j = 0; j < 4; ++j)
                rsum[j] += __shfl_xor(rsum[j], off);

#pragma unroll
        for (int j = 0; j < 4; ++j) l_i[j] = l_i[j] * alpha[j] + rsum[j];
#pragma unroll
        for (int n = 0; n < 4; ++n)
#pragma unroll
            for (int j = 0; j < 4; ++j) o_acc[n][j] *= alpha[j];

        // P -> LDS (bf16, swizzled), wave-local rows
#pragma unroll
        for (int j = 0; j < 4; ++j) {
            int rl  = g * 4 + j;
            int rg  = w * 16 + rl;
            int swz = (rl & 7) << 3;
#pragma unroll
            for (int n = 0; n < 4; ++n)
                Ps[rg * 64 + ((n * 16 + li) ^ swz)] = f2b(p[n][j]);
        }

        // O += P V
#pragma unroll
        for (int kk = 0; kk < 2; ++kk) {
            int rq = w * 16 + li;
            short8 pa = *(const short8*)(Ps + rq * 64 + (((kk * 4 + g) ^ (li & 7))) * 8);
#pragma unroll
            for (int n = 0; n < 4; ++n) {
                int rv = n * 16 + li;
                short8 vb = *(const short8*)(Vs + rv * 64 + (((kk * 4 + g) ^ (li & 7))) * 8);
                o_acc[n] = __builtin_amdgcn_mfma_f32_16x16x32_bf16(pa, vb, o_acc[n], 0, 0, 0);
            }
        }
    }

    float inv[4];
#pragma unroll
    for (int j = 0; j < 4; ++j) inv[j] = 1.f / l_i[j];
#pragma unroll
    for (int n = 0; n < 4; ++n)
#pragma unroll
        for (int j = 0; j < 4; ++j) {
            int rowq = qt * 64 + w * 16 + g * 4 + j;
            ctx[(size_t)(b * 2048 + rowq) * 1024 + h * 64 + n * 16 + li] = f2b(o_acc[n][j] * inv[j]);
        }
}

// ---------------------------------------------------------------------------
extern "C" void kernel_launch(void* const* d_in, const int* in_sizes, int n_in,
                              void* d_out, int out_size, void* d_ws, size_t ws_size,
                              hipStream_t stream) {
    const float* Q  = (const float*)d_in[0];
    const float* K  = (const float*)d_in[1];
    const float* V  = (const float*)d_in[2];
    const unsigned char* pmask = (const unsigned char*)d_in[3];
    const float* Wq = (const float*)d_in[4];
    const float* bq = (const float*)d_in[5];
    const float* Wk = (const float*)d_in[6];
    const float* bk = (const float*)d_in[7];
    const float* Wv = (const float*)d_in[8];
    const float* bv = (const float*)d_in[9];
    const float* Wo = (const float*)d_in[10];
    const float* bo = (const float*)d_in[11];
    const float* Wf = (const float*)d_in[12];
    const float* bf = (const float*)d_in[13];
    float* out = (float*)d_out;
    char*  ws  = (char*)d_ws;

    u16* WPQ = (u16*)(ws + WS_WPQ);  u16* WPK = (u16*)(ws + WS_WPK);
    u16* WPV = (u16*)(ws + WS_WPV);  u16* WBG = (u16*)(ws + WS_WBIG);
    float* BC = (float*)(ws + WS_BC);
    u16* QB = (u16*)(ws + WS_QB);  u16* KB = (u16*)(ws + WS_KB);  u16* VB = (u16*)(ws + WS_VB);
    u16* QP = (u16*)(ws + WS_QP);  u16* KP = (u16*)(ws + WS_KP);  u16* VP = (u16*)(ws + WS_VP);
    u16* VT = (u16*)(ws + WS_VT);  u16* CTX = (u16*)(ws + WS_CTX);

    conv_bf16<<<4096, 256, 0, stream>>>(Q, QB);
    conv_bf16<<<4096, 256, 0, stream>>>(K, KB);
    conv_bf16<<<4096, 256, 0, stream>>>(V, VB);
    pack_qkv<<<4096, 256, 0, stream>>>(Wq, Wk, Wv, WPQ, WPK, WPV);
    make_wbig<<<4096, 256, 0, stream>>>(Wo, Wf, WBG);
    make_bcomb<<<4, 256, 0, stream>>>(bo, bf, Wf, BC);

    dim3 g1(8, 64);
    gemm_bf16<1><<<g1, 256, 0, stream>>>(QB, WPQ, bq, QP, 8192, 1024, 1024);
    gemm_bf16<1><<<g1, 256, 0, stream>>>(KB, WPK, bk, KP, 8192, 1024, 1024);
    gemm_bf16<1><<<g1, 256, 0, stream>>>(VB, WPV, bv, VP, 8192, 1024, 1024);

    vtrans<<<dim3(32, 64), 256, 0, stream>>>(VP, VT);

    flash_attn<<<dim3(32, 64), 256, 0, stream>>>(QP, KP, VT, pmask, CTX);

    gemm_bf16<0><<<g1, 256, 0, stream>>>(CTX, WBG, BC, out, 8192, 1024, 1024);
}

// Round 3
// 471.699 us; speedup vs baseline: 4.9961x; 1.3207x over previous
//
#include <hip/hip_runtime.h>

typedef unsigned short u16;
typedef __attribute__((ext_vector_type(8))) short short8;
typedef __attribute__((ext_vector_type(4))) float f32x4;

#define NEG (-1e30f)
#define SCL 0.180336880f   // 0.125 / ln(2)  -> exp2 domain

// ---- workspace byte offsets -------------------------------------------------
#define WS_WPQ   (0u)          // 2 MB  bf16 [N=1024][K=1024]  (B^T)
#define WS_WPK   (2u<<20)
#define WS_WPV   (4u<<20)
#define WS_WBIG  (6u<<20)      // 2 MB  bf16 B^T
#define WS_BC    (8u<<20)      // 4 KB  f32
#define WS_QB    (9u<<20)      // 16 MB bf16 [8192][1024]
#define WS_KB    (25u<<20)
#define WS_VB    (41u<<20)
#define WS_QP    (57u<<20)     // q projection bf16
#define WS_KP    (73u<<20)
#define WS_VP    (89u<<20)
#define WS_VT    (105u<<20)    // V^T, pre-swizzled: [bh*64+dv][2048 kv]
#define WS_CTX   (121u<<20)    // attention out bf16

// ---- helpers ----------------------------------------------------------------
__device__ __forceinline__ u16 f2b(float f) {
    union { float f; unsigned u; } x; x.f = f;
    unsigned r = x.u + 0x7fffu + ((x.u >> 16) & 1u);   // RNE
    return (u16)(r >> 16);
}

__device__ __forceinline__ void gload16(const void* g, void* lds) {
    __builtin_amdgcn_global_load_lds(
        (const __attribute__((address_space(1))) void*)g,
        (__attribute__((address_space(3))) void*)lds, 16, 0, 0);
}

// ---- small prep kernels -----------------------------------------------------
__global__ __launch_bounds__(256) void conv_bf16(const float* __restrict__ in,
                                                 u16* __restrict__ out) {
    unsigned i = blockIdx.x * 256u + threadIdx.x;      // 1M threads, 8 elems each
    const float4* p = (const float4*)(in + (size_t)i * 8);
    float4 a = p[0], b = p[1];
    short8 o;
    o[0]=(short)f2b(a.x); o[1]=(short)f2b(a.y); o[2]=(short)f2b(a.z); o[3]=(short)f2b(a.w);
    o[4]=(short)f2b(b.x); o[5]=(short)f2b(b.y); o[6]=(short)f2b(b.z); o[7]=(short)f2b(b.w);
    *(short8*)(out + (size_t)i * 8) = o;
}

// Wq/Wk/Wv [H,D,64] -> B^T bf16 [n=h*64+kk][k=d]
__global__ __launch_bounds__(256) void pack_qkv(const float* __restrict__ Wq,
                                                const float* __restrict__ Wk,
                                                const float* __restrict__ Wv,
                                                u16* __restrict__ pq,
                                                u16* __restrict__ pk,
                                                u16* __restrict__ pv) {
    unsigned idx = blockIdx.x * 256u + threadIdx.x;    // 1M
    unsigned n = idx >> 10, d = idx & 1023u;
    unsigned h = n >> 6, kk = n & 63u;
    unsigned src = (h * 1024u + d) * 64u + kk;
    pq[idx] = f2b(Wq[src]);
    pk[idx] = f2b(Wk[src]);
    pv[idx] = f2b(Wv[src]);
}

// WbigT[n][k] = sum_u Wo[k][u] * Wf[(k/64)*64+u][n]   (bf16 out)
__global__ __launch_bounds__(256) void make_wbig(const float* __restrict__ Wo,
                                                 const float* __restrict__ Wf,
                                                 u16* __restrict__ wbig) {
    unsigned idx = blockIdx.x * 256u + threadIdx.x;    // 1M
    unsigned n = idx >> 10, k = idx & 1023u;
    unsigned h = k >> 6;
    float s = 0.f;
#pragma unroll 8
    for (int u = 0; u < 64; ++u)
        s += Wo[k * 64u + u] * Wf[(h * 64u + u) * 1024u + n];
    wbig[(size_t)n * 1024u + k] = f2b(s);
}

// bcomb[n] = bf[n] + sum_x bo[x] * Wf[x][n]
// 64 blocks; block owns n in [bn*16, bn*16+16). thread (tx=n-off, ty=x-chunk).
__global__ __launch_bounds__(256) void make_bcomb(const float* __restrict__ bo,
                                                  const float* __restrict__ bf,
                                                  const float* __restrict__ Wf,
                                                  float* __restrict__ bc) {
    __shared__ float red[16][17];
    const int tx = threadIdx.x & 15, ty = threadIdx.x >> 4;
    const int n = blockIdx.x * 16 + tx;
    float s = 0.f;
#pragma unroll
    for (int i = 0; i < 64; ++i) {
        int x = ty * 64 + i;
        s += bo[x] * Wf[(size_t)x * 1024 + n];
    }
    red[ty][tx] = s;
    __syncthreads();
    if (ty == 0) {
        float t = bf[n];
#pragma unroll
        for (int y = 0; y < 16; ++y) t += red[y][tx];
        bc[n] = t;
    }
}

// v bf16 [B,2048,1024] -> Vt bf16 [bh*64+dv][2048], kv-chunks XOR-swizzled by dv
__global__ __launch_bounds__(256) void vtrans(const u16* __restrict__ vp,
                                              u16* __restrict__ vt) {
    const int kvt = blockIdx.x, bh = blockIdx.y, b = bh >> 4, h = bh & 15;
    const int tid = threadIdx.x;
    __shared__ u16 T[64][72];
    {
        int kv_r = tid >> 2, dg = (tid & 3) * 16;
        const u16* src = vp + ((size_t)(b * 2048 + kvt * 64 + kv_r)) * 1024 + h * 64 + dg;
        short8 x0 = *(const short8*)src;
        short8 x1 = *(const short8*)(src + 8);
#pragma unroll
        for (int i = 0; i < 8; ++i) { T[dg + i][kv_r] = (u16)x0[i]; T[dg + 8 + i][kv_r] = (u16)x1[i]; }
    }
    __syncthreads();
    {
        int dv = tid >> 2, cg = (tid & 3) * 16;
        int swz = (dv & 7) << 3;
        u16* dst = vt + ((size_t)(bh * 64 + dv)) * 2048 + kvt * 64;
#pragma unroll
        for (int q = 0; q < 2; ++q) {
            int c0 = cg + q * 8;
            short8 y;
#pragma unroll
            for (int i = 0; i < 8; ++i) y[i] = (short)T[dv][c0 + i];
            *(short8*)(dst + (c0 ^ swz)) = y;
        }
    }
}

// ---- bf16 MFMA GEMM: C = A[M,K] @ Bt[N,K]^T + bias --------------------------
// 128x128 tile, BK=64, 4 waves, global_load_lds staging with XOR-swizzled source.
template <int OUT_BF16>
__global__ __launch_bounds__(256) void gemm_bf16(const u16* __restrict__ A,
                                                 const u16* __restrict__ Bt,
                                                 const float* __restrict__ bias,
                                                 void* __restrict__ Cv,
                                                 int M, int N, int K) {
    __shared__ __align__(16) u16 As[128 * 64];
    __shared__ __align__(16) u16 Bs[128 * 64];
    const int tid = threadIdx.x;
    const int lane = tid & 63, w = tid >> 6;
    const int li = lane & 15, g = lane >> 4;
    const int bm = blockIdx.y * 128, bn = blockIdx.x * 128;
    const int wm = w >> 1, wn = w & 1;

    f32x4 acc[4][4];
#pragma unroll
    for (int m = 0; m < 4; ++m)
#pragma unroll
        for (int n = 0; n < 4; ++n) acc[m][n] = (f32x4){0.f, 0.f, 0.f, 0.f};

    for (int k0 = 0; k0 < K; k0 += 64) {
        __syncthreads();
#pragma unroll
        for (int r = 0; r < 4; ++r) {
            int ch  = (r * 4 + w) * 64 + lane;          // 0..1023
            int row = ch >> 3;
            int ck  = (ch & 7) ^ (row & 7);             // pre-swizzled source chunk
            gload16(A  + (size_t)(bm + row) * K + k0 + ck * 8, (char*)As + (r * 4 + w) * 1024);
            gload16(Bt + (size_t)(bn + row) * K + k0 + ck * 8, (char*)Bs + (r * 4 + w) * 1024);
        }
        __syncthreads();
#pragma unroll
        for (int kk = 0; kk < 2; ++kk) {
            short8 a[4], b[4];
#pragma unroll
            for (int m = 0; m < 4; ++m) {
                int row = wm * 64 + m * 16 + li;
                int c = (kk * 4 + g) ^ (row & 7);
                a[m] = *(const short8*)(As + row * 64 + c * 8);
            }
#pragma unroll
            for (int n = 0; n < 4; ++n) {
                int row = wn * 64 + n * 16 + li;
                int c = (kk * 4 + g) ^ (row & 7);
                b[n] = *(const short8*)(Bs + row * 64 + c * 8);
            }
#pragma unroll
            for (int m = 0; m < 4; ++m)
#pragma unroll
                for (int n = 0; n < 4; ++n)
                    acc[m][n] = __builtin_amdgcn_mfma_f32_16x16x32_bf16(a[m], b[n], acc[m][n], 0, 0, 0);
        }
    }

#pragma unroll
    for (int n = 0; n < 4; ++n) {
        int col = bn + wn * 64 + n * 16 + li;
        float bv = bias[col];
#pragma unroll
        for (int m = 0; m < 4; ++m)
#pragma unroll
            for (int j = 0; j < 4; ++j) {
                int row = bm + wm * 64 + m * 16 + g * 4 + j;
                float v = acc[m][n][j] + bv;
                if (OUT_BF16) ((u16*)Cv)[(size_t)row * N + col] = f2b(v);
                else          ((float*)Cv)[(size_t)row * N + col] = v;
            }
    }
}

// ---- bf16 MFMA causal flash attention, double-buffered ----------------------
// grid (bh, qtile); 4 waves; wave w owns q rows [w*16, w*16+16).
// Schedule per iter: STAGE(next) -> QK -> softmax -> PV -> barrier.
__global__ __launch_bounds__(256) void flash_attn(const u16* __restrict__ qp,
                                                  const u16* __restrict__ kp,
                                                  const u16* __restrict__ vt,
                                                  const unsigned char* __restrict__ pmask,
                                                  u16* __restrict__ ctx) {
    const int bh = blockIdx.x, b = bh >> 4, h = bh & 15;
    const int qt = 31 - blockIdx.y;                    // longest blocks dispatch first
    const int tid = threadIdx.x, lane = tid & 63, w = tid >> 6;
    const int li = lane & 15, g = lane >> 4;

    __shared__ __align__(16) u16 Ks[2][64 * 64];
    __shared__ __align__(16) u16 Vs[2][64 * 64];
    __shared__ __align__(16) u16 Ps[64 * 64];

    auto STAGE = [&](int buf, int kt) {
#pragma unroll
        for (int r = 0; r < 2; ++r) {
            int ch  = (r * 4 + w) * 64 + lane;         // 0..511
            int row = ch >> 3, cc = ch & 7;
            int ck  = cc ^ (row & 7);
            gload16(kp + (size_t)(b * 2048 + kt * 64 + row) * 1024 + h * 64 + ck * 8,
                    (char*)(Ks[buf]) + (r * 4 + w) * 1024);
            gload16(vt + (size_t)(bh * 64 + row) * 2048 + kt * 64 + cc * 8,   // pre-swizzled
                    (char*)(Vs[buf]) + (r * 4 + w) * 1024);
        }
    };

    // prologue: stage kt=0; Q fragments straight to registers (per-lane global)
    STAGE(0, 0);
    const int rq = w * 16 + li;
    const u16* qg = qp + (size_t)(b * 2048 + qt * 64 + rq) * 1024 + h * 64;
    short8 aq0 = *(const short8*)(qg + g * 8);          // kk=0 chunk
    short8 aq1 = *(const short8*)(qg + 32 + g * 8);     // kk=1 chunk

    float m_i[4], l_i[4];
    f32x4 o_acc[4];
#pragma unroll
    for (int j = 0; j < 4; ++j) { m_i[j] = NEG; l_i[j] = 0.f; }
#pragma unroll
    for (int n = 0; n < 4; ++n) o_acc[n] = (f32x4){0.f, 0.f, 0.f, 0.f};

    const unsigned char* pm = pmask + (size_t)b * 2048;

    __syncthreads();   // drains vmcnt: Ks[0]/Vs[0] + Q regs ready
    int cur = 0;

    for (int kt = 0; kt <= qt; ++kt) {
        if (kt < qt) STAGE(cur ^ 1, kt + 1);           // overlap with this iter's compute

        // S = Q K^T
        f32x4 s[4];
#pragma unroll
        for (int n = 0; n < 4; ++n) s[n] = (f32x4){0.f, 0.f, 0.f, 0.f};
        __builtin_amdgcn_s_setprio(1);
#pragma unroll
        for (int kk = 0; kk < 2; ++kk) {
            short8 aq = kk ? aq1 : aq0;
#pragma unroll
            for (int n = 0; n < 4; ++n) {
                int rk = n * 16 + li;
                short8 bk = *(const short8*)(Ks[cur] + rk * 64 + (((kk * 4 + g) ^ (li & 7))) * 8);
                s[n] = __builtin_amdgcn_mfma_f32_16x16x32_bf16(aq, bk, s[n], 0, 0, 0);
            }
        }
        __builtin_amdgcn_s_setprio(0);

        // mask + scale (exp2 domain)
        float mcol[4];
#pragma unroll
        for (int n = 0; n < 4; ++n) mcol[n] = pm[kt * 64 + n * 16 + li] ? NEG : 0.f;
        const bool diag = (kt == qt);
        float rmax[4];
#pragma unroll
        for (int j = 0; j < 4; ++j) rmax[j] = NEG;
#pragma unroll
        for (int n = 0; n < 4; ++n) {
            int colk = kt * 64 + n * 16 + li;
#pragma unroll
            for (int j = 0; j < 4; ++j) {
                int rowq = qt * 64 + w * 16 + g * 4 + j;
                float v = s[n][j] * SCL + mcol[n];
                if (diag && colk > rowq) v = NEG;
                s[n][j] = v;
                rmax[j] = fmaxf(rmax[j], v);
            }
        }
#pragma unroll
        for (int off = 1; off < 16; off <<= 1)
#pragma unroll
            for (int j = 0; j < 4; ++j)
                rmax[j] = fmaxf(rmax[j], __shfl_xor(rmax[j], off));

        // T13: rescale only when a row max grew (wave-uniform vote)
        bool grow = (rmax[0] > m_i[0]) | (rmax[1] > m_i[1]) |
                    (rmax[2] > m_i[2]) | (rmax[3] > m_i[3]);
        if (__any(grow)) {
#pragma unroll
            for (int j = 0; j < 4; ++j) {
                float mn = fmaxf(m_i[j], rmax[j]);
                float a  = exp2f(m_i[j] - mn);
                m_i[j] = mn;
                l_i[j] *= a;
#pragma unroll
                for (int n = 0; n < 4; ++n) o_acc[n][j] *= a;
            }
        }

        float p[4][4], rsum[4] = {0.f, 0.f, 0.f, 0.f};
#pragma unroll
        for (int n = 0; n < 4; ++n)
#pragma unroll
            for (int j = 0; j < 4; ++j) {
                float pv = exp2f(s[n][j] - m_i[j]);
                p[n][j] = pv;
                rsum[j] += pv;
            }
#pragma unroll
        for (int off = 1; off < 16; off <<= 1)
#pragma unroll
            for (int j = 0; j < 4; ++j)
                rsum[j] += __shfl_xor(rsum[j], off);
#pragma unroll
        for (int j = 0; j < 4; ++j) l_i[j] += rsum[j];

        // P -> LDS (bf16, swizzled), wave-local rows (no barrier needed)
#pragma unroll
        for (int j = 0; j < 4; ++j) {
            int rl  = g * 4 + j;
            int rg  = w * 16 + rl;
            int swz = (rl & 7) << 3;
#pragma unroll
            for (int n = 0; n < 4; ++n)
                Ps[rg * 64 + ((n * 16 + li) ^ swz)] = f2b(p[n][j]);
        }

        // O += P V
        __builtin_amdgcn_s_setprio(1);
#pragma unroll
        for (int kk = 0; kk < 2; ++kk) {
            short8 pa = *(const short8*)(Ps + rq * 64 + (((kk * 4 + g) ^ (li & 7))) * 8);
#pragma unroll
            for (int n = 0; n < 4; ++n) {
                int rv = n * 16 + li;
                short8 vb = *(const short8*)(Vs[cur] + rv * 64 + (((kk * 4 + g) ^ (li & 7))) * 8);
                o_acc[n] = __builtin_amdgcn_mfma_f32_16x16x32_bf16(pa, vb, o_acc[n], 0, 0, 0);
            }
        }
        __builtin_amdgcn_s_setprio(0);

        __syncthreads();   // drains vmcnt (next tile landed) + all waves done with cur
        cur ^= 1;
    }

    float inv[4];
#pragma unroll
    for (int j = 0; j < 4; ++j) inv[j] = 1.f / l_i[j];
#pragma unroll
    for (int n = 0; n < 4; ++n)
#pragma unroll
        for (int j = 0; j < 4; ++j) {
            int rowq = qt * 64 + w * 16 + g * 4 + j;
            ctx[(size_t)(b * 2048 + rowq) * 1024 + h * 64 + n * 16 + li] = f2b(o_acc[n][j] * inv[j]);
        }
}

// ---------------------------------------------------------------------------
extern "C" void kernel_launch(void* const* d_in, const int* in_sizes, int n_in,
                              void* d_out, int out_size, void* d_ws, size_t ws_size,
                              hipStream_t stream) {
    const float* Q  = (const float*)d_in[0];
    const float* K  = (const float*)d_in[1];
    const float* V  = (const float*)d_in[2];
    const unsigned char* pmask = (const unsigned char*)d_in[3];
    const float* Wq = (const float*)d_in[4];
    const float* bq = (const float*)d_in[5];
    const float* Wk = (const float*)d_in[6];
    const float* bk = (const float*)d_in[7];
    const float* Wv = (const float*)d_in[8];
    const float* bv = (const float*)d_in[9];
    const float* Wo = (const float*)d_in[10];
    const float* bo = (const float*)d_in[11];
    const float* Wf = (const float*)d_in[12];
    const float* bf = (const float*)d_in[13];
    float* out = (float*)d_out;
    char*  ws  = (char*)d_ws;

    u16* WPQ = (u16*)(ws + WS_WPQ);  u16* WPK = (u16*)(ws + WS_WPK);
    u16* WPV = (u16*)(ws + WS_WPV);  u16* WBG = (u16*)(ws + WS_WBIG);
    float* BC = (float*)(ws + WS_BC);
    u16* QB = (u16*)(ws + WS_QB);  u16* KB = (u16*)(ws + WS_KB);  u16* VB = (u16*)(ws + WS_VB);
    u16* QP = (u16*)(ws + WS_QP);  u16* KP = (u16*)(ws + WS_KP);  u16* VP = (u16*)(ws + WS_VP);
    u16* VT = (u16*)(ws + WS_VT);  u16* CTX = (u16*)(ws + WS_CTX);

    conv_bf16<<<4096, 256, 0, stream>>>(Q, QB);
    conv_bf16<<<4096, 256, 0, stream>>>(K, KB);
    conv_bf16<<<4096, 256, 0, stream>>>(V, VB);
    pack_qkv<<<4096, 256, 0, stream>>>(Wq, Wk, Wv, WPQ, WPK, WPV);
    make_wbig<<<4096, 256, 0, stream>>>(Wo, Wf, WBG);
    make_bcomb<<<64, 256, 0, stream>>>(bo, bf, Wf, BC);

    dim3 g1(8, 64);
    gemm_bf16<1><<<g1, 256, 0, stream>>>(QB, WPQ, bq, QP, 8192, 1024, 1024);
    gemm_bf16<1><<<g1, 256, 0, stream>>>(KB, WPK, bk, KP, 8192, 1024, 1024);
    gemm_bf16<1><<<g1, 256, 0, stream>>>(VB, WPV, bv, VP, 8192, 1024, 1024);

    vtrans<<<dim3(32, 64), 256, 0, stream>>>(VP, VT);

    flash_attn<<<dim3(64, 32), 256, 0, stream>>>(QP, KP, VT, pmask, CTX);

    gemm_bf16<0><<<g1, 256, 0, stream>>>(CTX, WBG, BC, out, 8192, 1024, 1024);
}

// Round 4
// 401.945 us; speedup vs baseline: 5.8631x; 1.1735x over previous
//
#include <hip/hip_runtime.h>

typedef unsigned short u16;
typedef unsigned int u32;
typedef __attribute__((ext_vector_type(8))) short short8;
typedef __attribute__((ext_vector_type(4))) float f32x4;

#define NEG (-1e30f)
#define SCL 0.180336880f   // 0.125 / ln(2)  -> exp2 domain

// ---- workspace byte offsets -------------------------------------------------
#define WS_WPQ   (0u)          // 2 MB  bf16 [N=1024][K=1024]  (B^T)
#define WS_WPK   (2u<<20)
#define WS_WPV   (4u<<20)
#define WS_WBIG  (6u<<20)      // 2 MB  bf16 B^T
#define WS_BC    (8u<<20)               // 4 KB f32
#define WS_MB    ((8u<<20)+(1u<<16))    // 32 KB f32 mask bias [B][2048]
#define WS_MP    ((8u<<20)+(3u<<16))    // 128 B int mask partials
#define WS_QB    (9u<<20)      // 16 MB bf16 [8192][1024]
#define WS_KB    (25u<<20)
#define WS_VB    (41u<<20)
#define WS_QP    (57u<<20)     // q projection bf16 (PRE-SCALED by SCL)
#define WS_KP    (73u<<20)
#define WS_VP    (89u<<20)
#define WS_VT    (105u<<20)    // V^T, pre-swizzled: [bh*64+dv][2048 kv]
#define WS_CTX   (121u<<20)    // attention out bf16

// ---- helpers ----------------------------------------------------------------
__device__ __forceinline__ u16 f2b(float f) {
    union { float f; unsigned u; } x; x.f = f;
    unsigned r = x.u + 0x7fffu + ((x.u >> 16) & 1u);   // RNE
    return (u16)(r >> 16);
}

__device__ __forceinline__ u32 cvt_pk(float a, float b) {   // low16=bf16(a), high16=bf16(b)
    u32 r;
    asm("v_cvt_pk_bf16_f32 %0, %1, %2" : "=v"(r) : "v"(a), "v"(b));
    return r;
}

__device__ __forceinline__ void gload16(const void* g, void* lds) {
    __builtin_amdgcn_global_load_lds(
        (const __attribute__((address_space(1))) void*)g,
        (__attribute__((address_space(3))) void*)lds, 16, 0, 0);
}

// ---- small prep kernels -----------------------------------------------------
__global__ __launch_bounds__(256) void conv_bf16(const float* __restrict__ in,
                                                 u16* __restrict__ out) {
    unsigned i = blockIdx.x * 256u + threadIdx.x;
    const float4* p = (const float4*)(in + (size_t)i * 8);
    float4 a = p[0], b = p[1];
    short8 o;
    o[0]=(short)f2b(a.x); o[1]=(short)f2b(a.y); o[2]=(short)f2b(a.z); o[3]=(short)f2b(a.w);
    o[4]=(short)f2b(b.x); o[5]=(short)f2b(b.y); o[6]=(short)f2b(b.z); o[7]=(short)f2b(b.w);
    *(short8*)(out + (size_t)i * 8) = o;
}

// Wq/Wk/Wv [H,D,64] -> B^T bf16 [n=h*64+kk][k=d], LDS-transposed (coalesced)
// grid (16 d-tiles, 16 heads)
__global__ __launch_bounds__(256) void pack_qkv(const float* __restrict__ Wq,
                                                const float* __restrict__ Wk,
                                                const float* __restrict__ Wv,
                                                u16* __restrict__ pq,
                                                u16* __restrict__ pk,
                                                u16* __restrict__ pv) {
    __shared__ u16 T[64][68];
    const int dt = blockIdx.x, h = blockIdx.y;
    const int r = threadIdx.x >> 2, c0 = (threadIdx.x & 3) * 16;
    const float* srcs[3] = {Wq, Wk, Wv};
    u16* dsts[3] = {pq, pk, pv};
#pragma unroll
    for (int m = 0; m < 3; ++m) {
        const float* src = srcs[m] + (size_t)(h * 1024 + dt * 64 + r) * 64 + c0;
#pragma unroll
        for (int i4 = 0; i4 < 4; ++i4) {
            float4 x = *(const float4*)(src + i4 * 4);
            T[c0 + i4*4 + 0][r] = f2b(x.x);
            T[c0 + i4*4 + 1][r] = f2b(x.y);
            T[c0 + i4*4 + 2][r] = f2b(x.z);
            T[c0 + i4*4 + 3][r] = f2b(x.w);
        }
        __syncthreads();
        u16* dst = dsts[m] + (size_t)(h * 64 + r) * 1024 + dt * 64 + c0;
        short8 o0, o1;
#pragma unroll
        for (int i = 0; i < 8; ++i) { o0[i] = (short)T[r][c0 + i]; o1[i] = (short)T[r][c0 + 8 + i]; }
        *(short8*)dst = o0;
        *(short8*)(dst + 8) = o1;
        __syncthreads();
    }
}

// WbigT[n][k=h*64+v] = sum_u Wo[h][v][u] * Wf[h*64+u][n]; grid (4 col-tiles, 16 h)
__global__ __launch_bounds__(256) void make_wbig(const float* __restrict__ Wo,
                                                 const float* __restrict__ Wf,
                                                 u16* __restrict__ wbig) {
    __shared__ float WoL[64][64];
    const int ct = blockIdx.x, h = blockIdx.y;
    const int tid = threadIdx.x;
#pragma unroll
    for (int r = 0; r < 16; ++r) {
        int i = r * 256 + tid;
        WoL[i >> 6][i & 63] = Wo[h * 4096 + i];
    }
    __syncthreads();
    const int n = ct * 256 + tid;
    float wf[64];
#pragma unroll
    for (int u = 0; u < 64; ++u)
        wf[u] = Wf[(size_t)(h * 64 + u) * 1024 + n];
    u16* dst = wbig + (size_t)n * 1024 + h * 64;
    for (int vb = 0; vb < 64; vb += 8) {
        short8 o;
#pragma unroll
        for (int t = 0; t < 8; ++t) {
            int v = vb + t;
            float s = 0.f;
#pragma unroll
            for (int u4 = 0; u4 < 16; ++u4) {
                float4 w4 = *(const float4*)&WoL[v][u4 * 4];
                s += w4.x * wf[u4*4] + w4.y * wf[u4*4+1] + w4.z * wf[u4*4+2] + w4.w * wf[u4*4+3];
            }
            o[t] = (short)f2b(s);
        }
        *(short8*)(dst + vb) = o;
    }
}

// bcomb[n] = bf[n] + sum_x bo[x]*Wf[x][n]; also pmask -> mbias f32 + mpart flags
__global__ __launch_bounds__(256) void make_bcomb(const float* __restrict__ bo,
                                                  const float* __restrict__ bf,
                                                  const float* __restrict__ Wf,
                                                  const unsigned char* __restrict__ pmask,
                                                  float* __restrict__ bc,
                                                  float* __restrict__ mbias,
                                                  int* __restrict__ mpart) {
    __shared__ float red[16][17];
    const int tx = threadIdx.x & 15, ty = threadIdx.x >> 4;
    const int n = blockIdx.x * 16 + tx;
    float s = 0.f;
#pragma unroll
    for (int i = 0; i < 64; ++i) {
        int x = ty * 64 + i;
        s += bo[x] * Wf[(size_t)x * 1024 + n];
    }
    red[ty][tx] = s;

    int t = blockIdx.x * 256 + threadIdx.x;
    int v = 0;
    if (t < 8192) {
        v = pmask[t] ? 1 : 0;
        mbias[t] = v ? NEG : 0.f;
    }
    int ba = __syncthreads_or(v);
    if (threadIdx.x == 0 && blockIdx.x < 32) mpart[blockIdx.x] = ba;

    if (ty == 0) {
        float tt = bf[n];
#pragma unroll
        for (int y = 0; y < 16; ++y) tt += red[y][tx];
        bc[n] = tt;
    }
}

// v bf16 [B,2048,1024] -> Vt bf16 [bh*64+dv][2048], kv-chunks XOR-swizzled by dv
__global__ __launch_bounds__(256) void vtrans(const u16* __restrict__ vp,
                                              u16* __restrict__ vt) {
    const int kvt = blockIdx.x, bh = blockIdx.y, b = bh >> 4, h = bh & 15;
    const int tid = threadIdx.x;
    __shared__ u16 T[64][72];
    {
        int kv_r = tid >> 2, dg = (tid & 3) * 16;
        const u16* src = vp + ((size_t)(b * 2048 + kvt * 64 + kv_r)) * 1024 + h * 64 + dg;
        short8 x0 = *(const short8*)src;
        short8 x1 = *(const short8*)(src + 8);
#pragma unroll
        for (int i = 0; i < 8; ++i) { T[dg + i][kv_r] = (u16)x0[i]; T[dg + 8 + i][kv_r] = (u16)x1[i]; }
    }
    __syncthreads();
    {
        int dv = tid >> 2, cg = (tid & 3) * 16;
        int swz = (dv & 7) << 3;
        u16* dst = vt + ((size_t)(bh * 64 + dv)) * 2048 + kvt * 64;
#pragma unroll
        for (int q = 0; q < 2; ++q) {
            int c0 = cg + q * 8;
            short8 y;
#pragma unroll
            for (int i = 0; i < 8; ++i) y[i] = (short)T[dv][c0 + i];
            *(short8*)(dst + (c0 ^ swz)) = y;
        }
    }
}

// ---- bf16 MFMA GEMM, double-buffered: C = (A @ Bt^T + bias) * oscale --------
template <int OUT_BF16>
__global__ __launch_bounds__(256) void gemm_bf16(const u16* __restrict__ A,
                                                 const u16* __restrict__ Bt,
                                                 const float* __restrict__ bias,
                                                 void* __restrict__ Cv,
                                                 int M, int N, int K, float oscale) {
    __shared__ __align__(16) u16 As[2][128 * 64];
    __shared__ __align__(16) u16 Bs[2][128 * 64];
    const int tid = threadIdx.x;
    const int lane = tid & 63, w = tid >> 6;
    const int li = lane & 15, g = lane >> 4;
    const int bm = blockIdx.y * 128, bn = blockIdx.x * 128;
    const int wm = w >> 1, wn = w & 1;

    auto STAGE = [&](int buf, int k0) {
#pragma unroll
        for (int r = 0; r < 4; ++r) {
            int ch  = (r * 4 + w) * 64 + lane;
            int row = ch >> 3;
            int ck  = (ch & 7) ^ (row & 7);
            gload16(A  + (size_t)(bm + row) * K + k0 + ck * 8, (char*)(As[buf]) + (r * 4 + w) * 1024);
            gload16(Bt + (size_t)(bn + row) * K + k0 + ck * 8, (char*)(Bs[buf]) + (r * 4 + w) * 1024);
        }
    };

    f32x4 acc[4][4];
#pragma unroll
    for (int m = 0; m < 4; ++m)
#pragma unroll
        for (int n = 0; n < 4; ++n) acc[m][n] = (f32x4){0.f, 0.f, 0.f, 0.f};

    STAGE(0, 0);
    __syncthreads();
    int cur = 0;

    for (int k0 = 0; k0 < K; k0 += 64) {
        if (k0 + 64 < K) STAGE(cur ^ 1, k0 + 64);
#pragma unroll
        for (int kk = 0; kk < 2; ++kk) {
            short8 a[4], b[4];
#pragma unroll
            for (int m = 0; m < 4; ++m) {
                int row = wm * 64 + m * 16 + li;
                int c = (kk * 4 + g) ^ (row & 7);
                a[m] = *(const short8*)(As[cur] + row * 64 + c * 8);
            }
#pragma unroll
            for (int n = 0; n < 4; ++n) {
                int row = wn * 64 + n * 16 + li;
                int c = (kk * 4 + g) ^ (row & 7);
                b[n] = *(const short8*)(Bs[cur] + row * 64 + c * 8);
            }
#pragma unroll
            for (int m = 0; m < 4; ++m)
#pragma unroll
                for (int n = 0; n < 4; ++n)
                    acc[m][n] = __builtin_amdgcn_mfma_f32_16x16x32_bf16(a[m], b[n], acc[m][n], 0, 0, 0);
        }
        __syncthreads();
        cur ^= 1;
    }

#pragma unroll
    for (int n = 0; n < 4; ++n) {
        int col = bn + wn * 64 + n * 16 + li;
        float bv = bias[col];
#pragma unroll
        for (int m = 0; m < 4; ++m)
#pragma unroll
            for (int j = 0; j < 4; ++j) {
                int row = bm + wm * 64 + m * 16 + g * 4 + j;
                float v = (acc[m][n][j] + bv) * oscale;
                if (OUT_BF16) ((u16*)Cv)[(size_t)row * N + col] = f2b(v);
                else          ((float*)Cv)[(size_t)row * N + col] = v;
            }
    }
}

// ---- bf16 MFMA causal flash attention, swapped-QK softmax -------------------
// grid (bh, qtile); 4 waves; wave w owns q rows [w*16, w*16+16).
// Swapped QK^T: s = mfma(K,Q) -> lane holds S[q=w*16+li][k=n*16+g*4+j]:
// per-lane scalar m/l state, 2-shfl reductions, k-contiguous P packing.
__global__ __launch_bounds__(256) void flash_attn(const u16* __restrict__ qp,
                                                  const u16* __restrict__ kp,
                                                  const u16* __restrict__ vt,
                                                  const float* __restrict__ mbias,
                                                  const int* __restrict__ mpart,
                                                  u16* __restrict__ ctx) {
    const int bh = blockIdx.x, b = bh >> 4, h = bh & 15;
    const int qt = 31 - blockIdx.y;                    // longest blocks dispatch first
    const int tid = threadIdx.x, lane = tid & 63, w = tid >> 6;
    const int li = lane & 15, g = lane >> 4;

    __shared__ __align__(16) u16 Ks[2][64 * 64];
    __shared__ __align__(16) u16 Vs[2][64 * 64];
    __shared__ __align__(16) u16 Ps[64 * 64];

    auto STAGE = [&](int buf, int kt) {
#pragma unroll
        for (int r = 0; r < 2; ++r) {
            int ch  = (r * 4 + w) * 64 + lane;
            int row = ch >> 3, cc = ch & 7;
            int ck  = cc ^ (row & 7);
            gload16(kp + (size_t)(b * 2048 + kt * 64 + row) * 1024 + h * 64 + ck * 8,
                    (char*)(Ks[buf]) + (r * 4 + w) * 1024);
            gload16(vt + (size_t)(bh * 64 + row) * 2048 + kt * 64 + cc * 8,
                    (char*)(Vs[buf]) + (r * 4 + w) * 1024);
        }
    };

    STAGE(0, 0);
    // Q fragments straight to registers (pre-scaled by SCL at projection)
    const int rq = w * 16 + li;
    const u16* qg = qp + (size_t)(b * 2048 + qt * 64 + rq) * 1024 + h * 64;
    short8 aq0 = *(const short8*)(qg + g * 8);
    short8 aq1 = *(const short8*)(qg + 32 + g * 8);

    bool padded;
    {
        int a = 0;
#pragma unroll
        for (int i = 0; i < 8; ++i) a |= mpart[b * 8 + i];
        padded = (a != 0);
    }

    float m_i = NEG, l_i = 0.f;
    f32x4 o_acc[4];
#pragma unroll
    for (int n = 0; n < 4; ++n) o_acc[n] = (f32x4){0.f, 0.f, 0.f, 0.f};

    const float* mb = mbias + (size_t)b * 2048;
    const int swz = li & 7;   // all LDS rows this lane touches have row&7 == li&7

    __syncthreads();   // drains vmcnt: Ks[0]/Vs[0] + Q regs ready
    int cur = 0;

    auto TILE = [&](int kt, int buf, bool diag) {
        float mcv[16];
        if (padded) {
#pragma unroll
            for (int n = 0; n < 4; ++n)
                *(float4*)(mcv + n * 4) = *(const float4*)(mb + kt * 64 + n * 16 + g * 4);
        }

        // S^T block: s[n][j] = S[q=w*16+li][k=n*16+g*4+j]
        f32x4 s[4];
#pragma unroll
        for (int n = 0; n < 4; ++n) s[n] = (f32x4){0.f, 0.f, 0.f, 0.f};
        __builtin_amdgcn_s_setprio(1);
#pragma unroll
        for (int kk = 0; kk < 2; ++kk) {
            short8 aq = kk ? aq1 : aq0;
#pragma unroll
            for (int n = 0; n < 4; ++n) {
                short8 bk = *(const short8*)(Ks[buf] + (n * 16 + li) * 64 + ((kk * 4 + g) ^ swz) * 8);
                s[n] = __builtin_amdgcn_mfma_f32_16x16x32_bf16(bk, aq, s[n], 0, 0, 0);
            }
        }
        __builtin_amdgcn_s_setprio(0);

        // mask + per-lane row max (whole row lives in 4 lanes: this one + xor16/32)
        float rmax = NEG;
#pragma unroll
        for (int n = 0; n < 4; ++n)
#pragma unroll
            for (int j = 0; j < 4; ++j) {
                float v = s[n][j];
                if (padded) v += mcv[n * 4 + j];
                if (diag && (n * 16 + g * 4 + j) > rq) v = NEG;
                s[n][j] = v;
                rmax = fmaxf(rmax, v);
            }
        rmax = fmaxf(rmax, __shfl_xor(rmax, 16));
        rmax = fmaxf(rmax, __shfl_xor(rmax, 32));

        if (__any(rmax > m_i)) {
            float mn = fmaxf(m_i, rmax);
            float a  = exp2f(m_i - mn);
            m_i = mn;
            l_i *= a;
            float af[4];
#pragma unroll
            for (int j = 0; j < 4; ++j) af[j] = __shfl(a, g * 4 + j);  // alpha of o_acc's rows
#pragma unroll
            for (int n = 0; n < 4; ++n)
#pragma unroll
                for (int j = 0; j < 4; ++j) o_acc[n][j] *= af[j];
        }

        // P = exp2(S - m); pack pairs with v_cvt_pk_bf16_f32; 4x ds_write_b64
        float rs = 0.f;
#pragma unroll
        for (int n = 0; n < 4; ++n) {
            float p0 = exp2f(s[n][0] - m_i);
            float p1 = exp2f(s[n][1] - m_i);
            float p2 = exp2f(s[n][2] - m_i);
            float p3 = exp2f(s[n][3] - m_i);
            rs += (p0 + p1) + (p2 + p3);
            u32 lo = cvt_pk(p0, p1), hi = cvt_pk(p2, p3);
            int col = (n * 16 + g * 4) ^ (swz << 3);
            *(uint2*)(Ps + rq * 64 + col) = make_uint2(lo, hi);
        }
        rs += __shfl_xor(rs, 16);
        rs += __shfl_xor(rs, 32);
        l_i += rs;

        // O += P V  (P rows are wave-local: no barrier needed)
        __builtin_amdgcn_s_setprio(1);
#pragma unroll
        for (int kk = 0; kk < 2; ++kk) {
            short8 pa = *(const short8*)(Ps + rq * 64 + ((kk * 4 + g) ^ swz) * 8);
#pragma unroll
            for (int n = 0; n < 4; ++n) {
                short8 vb = *(const short8*)(Vs[buf] + (n * 16 + li) * 64 + ((kk * 4 + g) ^ swz) * 8);
                o_acc[n] = __builtin_amdgcn_mfma_f32_16x16x32_bf16(pa, vb, o_acc[n], 0, 0, 0);
            }
        }
        __builtin_amdgcn_s_setprio(0);
    };

    for (int kt = 0; kt < qt; ++kt) {                  // full tiles, no causal mask
        STAGE(cur ^ 1, kt + 1);
        TILE(kt, cur, false);
        __syncthreads();                               // next tile landed + cur free
        cur ^= 1;
    }
    TILE(qt, cur, true);                               // diagonal tile

    // epilogue: o_acc rows are g*4+j; their l comes from lanes li==row
    float linv = 1.f / l_i;
    float lr[4];
#pragma unroll
    for (int j = 0; j < 4; ++j) lr[j] = __shfl(linv, g * 4 + j);
#pragma unroll
    for (int n = 0; n < 4; ++n)
#pragma unroll
        for (int j = 0; j < 4; ++j) {
            int rowq = qt * 64 + w * 16 + g * 4 + j;
            ctx[(size_t)(b * 2048 + rowq) * 1024 + h * 64 + n * 16 + li] = f2b(o_acc[n][j] * lr[j]);
        }
}

// ---------------------------------------------------------------------------
extern "C" void kernel_launch(void* const* d_in, const int* in_sizes, int n_in,
                              void* d_out, int out_size, void* d_ws, size_t ws_size,
                              hipStream_t stream) {
    const float* Q  = (const float*)d_in[0];
    const float* K  = (const float*)d_in[1];
    const float* V  = (const float*)d_in[2];
    const unsigned char* pmask = (const unsigned char*)d_in[3];
    const float* Wq = (const float*)d_in[4];
    const float* bq = (const float*)d_in[5];
    const float* Wk = (const float*)d_in[6];
    const float* bk = (const float*)d_in[7];
    const float* Wv = (const float*)d_in[8];
    const float* bv = (const float*)d_in[9];
    const float* Wo = (const float*)d_in[10];
    const float* bo = (const float*)d_in[11];
    const float* Wf = (const float*)d_in[12];
    const float* bf = (const float*)d_in[13];
    float* out = (float*)d_out;
    char*  ws  = (char*)d_ws;

    u16* WPQ = (u16*)(ws + WS_WPQ);  u16* WPK = (u16*)(ws + WS_WPK);
    u16* WPV = (u16*)(ws + WS_WPV);  u16* WBG = (u16*)(ws + WS_WBIG);
    float* BC = (float*)(ws + WS_BC);
    float* MB = (float*)(ws + WS_MB);
    int*   MP = (int*)(ws + WS_MP);
    u16* QB = (u16*)(ws + WS_QB);  u16* KB = (u16*)(ws + WS_KB);  u16* VB = (u16*)(ws + WS_VB);
    u16* QP = (u16*)(ws + WS_QP);  u16* KP = (u16*)(ws + WS_KP);  u16* VP = (u16*)(ws + WS_VP);
    u16* VT = (u16*)(ws + WS_VT);  u16* CTX = (u16*)(ws + WS_CTX);

    conv_bf16<<<4096, 256, 0, stream>>>(Q, QB);
    conv_bf16<<<4096, 256, 0, stream>>>(K, KB);
    conv_bf16<<<4096, 256, 0, stream>>>(V, VB);
    pack_qkv<<<dim3(16, 16), 256, 0, stream>>>(Wq, Wk, Wv, WPQ, WPK, WPV);
    make_wbig<<<dim3(4, 16), 256, 0, stream>>>(Wo, Wf, WBG);
    make_bcomb<<<64, 256, 0, stream>>>(bo, bf, Wf, pmask, BC, MB, MP);

    dim3 g1(8, 64);
    gemm_bf16<1><<<g1, 256, 0, stream>>>(QB, WPQ, bq, QP, 8192, 1024, 1024, SCL);
    gemm_bf16<1><<<g1, 256, 0, stream>>>(KB, WPK, bk, KP, 8192, 1024, 1024, 1.0f);
    gemm_bf16<1><<<g1, 256, 0, stream>>>(VB, WPV, bv, VP, 8192, 1024, 1024, 1.0f);

    vtrans<<<dim3(32, 64), 256, 0, stream>>>(VP, VT);

    flash_attn<<<dim3(64, 32), 256, 0, stream>>>(QP, KP, VT, MB, MP, CTX);

    gemm_bf16<0><<<g1, 256, 0, stream>>>(CTX, WBG, BC, out, 8192, 1024, 1024, 1.0f);
}